// Round 3
// baseline (205.856 us; speedup 1.0000x reference)
//
#include <hip/hip_runtime.h>
#include <hip/hip_bf16.h>
#include <cstdint>

// MxDNA deformable conv block, MI355X/gfx950.
// K1: per-token tap coefficients; K2: W repack to bf16 [d][k*256+e];
// K3: fused gather-lerp + bf16 MFMA GEMM (M=65536, N=256, Kred=768).
// Round 4: double-buffered LDS (1 barrier/iter), reg prefetch distance 2.
// Round 5: XCD-aware bijective block swizzle (FETCH 203->69 MB).
// Round 6: BM64xBN256, 512thr, each token gathered once (62.5 us).
// Round 7: LDS-pipe attack. R6 accounting: ~816 LDS-cyc per block-iter vs
// 80 MFMA-cyc -> LDS ~62% busy incl. 8.65M conflict-cycles; the fattest
// pipe. Fix: (a) B fragments read DIRECT from L2-resident WB (384 KB,
// per-wave-private 64-row slice, static addresses, reg prefetch dist 1)
// -- no Bs LDS at all; (b) wave tile 32x64 -> 64x64 (4 waves, 256 thr):
// 16 MFMA per 4 A ds_reads. LDS/block = 10 KB, A-only dbuf, 1 barrier/iter.

#define N_TOK 8192
#define DIM   256
#define KW    768        // reduction length K*D
#define BM    64
#define BN    256
#define BK    32

typedef unsigned short u16;
typedef __attribute__((ext_vector_type(4))) float    floatx4;
typedef __attribute__((ext_vector_type(8))) __bf16   bf16x8;
typedef __attribute__((ext_vector_type(8))) u16      ushortx8;

__device__ __forceinline__ u16 f32_to_bf16_rne(float f) {
    uint32_t u = __float_as_uint(f);
    u += 0x7fffu + ((u >> 16) & 1u);
    return (u16)(u >> 16);
}

// ---------------- Kernel 1: per-token coefficients ----------------
__global__ __launch_bounds__(256) void coef_kernel(
    const float* __restrict__ x, const float* __restrict__ offw,
    const float* __restrict__ modw, int4* __restrict__ coef)
{
    const int wave = threadIdx.x >> 6;
    const int lane = threadIdx.x & 63;
    const int t = blockIdx.x * 4 + wave;

    const float4 xv = ((const float4*)(x + (size_t)t * DIM))[lane];
    float s[6];
#pragma unroll
    for (int k = 0; k < 3; ++k) {
        float4 wv = ((const float4*)(offw + k * DIM))[lane];
        s[k]     = xv.x * wv.x + xv.y * wv.y + xv.z * wv.z + xv.w * wv.w;
        float4 mv = ((const float4*)(modw + k * DIM))[lane];
        s[3 + k] = xv.x * mv.x + xv.y * mv.y + xv.z * mv.z + xv.w * mv.w;
    }
#pragma unroll
    for (int d = 1; d < 64; d <<= 1) {
#pragma unroll
        for (int i = 0; i < 6; ++i) s[i] += __shfl_xor(s[i], d, 64);
    }
    if (lane < 3) {
        const int k = lane;
        const int n = t & (N_TOK - 1);
        float pos   = (float)(n + k - 1) + s[k];
        bool  valid = (pos >= 0.0f) && (pos < (float)N_TOK);
        float ff = floorf(pos);
        ff = fminf(fmaxf(ff, 0.0f), (float)(N_TOK - 1));
        int   fi = (int)ff;
        int   ci = min(fi + 1, N_TOK - 1);
        float wc = pos - ff;
        float m  = valid ? (1.0f / (1.0f + expf(-s[3 + k]))) : 0.0f;
        coef[t * 3 + k] = make_int4(fi, ci,
                                    __float_as_int((1.0f - wc) * m),
                                    __float_as_int(wc * m));
    }
}

// ---------------- Kernel 2: repack weight to bf16 WB[d][k*256+e] ----------------
__global__ __launch_bounds__(256) void packw_kernel(
    const float* __restrict__ W, u16* __restrict__ WB)
{
    const int d = blockIdx.x;
    const int e = threadIdx.x;
#pragma unroll
    for (int k = 0; k < 3; ++k)
        WB[d * KW + k * DIM + e] = f32_to_bf16_rne(W[d * KW + e * 3 + k]);
}

// ---------------- Kernel 3: fused gather/lerp + MFMA GEMM ----------------
// block = 256 thr (4 waves), tile 64(M) x 256(N), BK=32, 24 K-iters.
// Wave tile 64x64: acc 4x4 frags (64 VGPR). A in LDS (dbuf, rows padded to
// 40 shorts); B fragments direct from global WB (L2-resident), register
// prefetch distance 1. A-gather register prefetch distance 2.
__global__ __launch_bounds__(256, 3) void deform_gemm_kernel(
    const float* __restrict__ x, const u16* __restrict__ WB,
    const int4* __restrict__ coef, float* __restrict__ out)
{
    __shared__ __align__(16) u16 As[2][BM * 40];   // 2 x 5120 B

    const int tid  = threadIdx.x;
    const int wave = tid >> 6;
    const int lane = tid & 63;

    // XCD-aware bijective swizzle: 1024 blocks, hw xcd = b % 8.
    // XCD x owns mtiles [x*128, (x+1)*128) == batch x.
    const int raw   = blockIdx.x;
    const int xcd   = raw & 7;
    const int lidx  = raw >> 3;              // 0..127 within XCD
    const int mtile = xcd * 128 + lidx;
    const int t0 = mtile * BM;
    const float* xb = x + (size_t)(t0 / N_TOK) * N_TOK * DIM;  // batch base (BM | N_TOK)

    // A staging role: token tl (0..63), 8-float column segment sub (0..3)
    const int tl  = tid >> 2;
    const int sub = tid & 3;

    const int wn   = wave * 64;       // wave's private 64-col N slice
    const int lrow = lane & 15;
    const int lq   = lane >> 4;

    // per-thread coefficients for token t0+tl (3 taps) — registers
    const int4 cc0 = coef[(size_t)(t0 + tl) * 3 + 0];
    const int4 cc1 = coef[(size_t)(t0 + tl) * 3 + 1];
    const int4 cc2 = coef[(size_t)(t0 + tl) * 3 + 2];

    // B fragment base: row wn+j*16+lrow, k-cols lq*8.. (advance by kk*32)
    const u16* bbase = WB + (size_t)(wn + lrow) * KW + lq * 8;

    // prefetch registers
    float4 pf0, pf1, pc0, pc1;     // A gather (slice kk+2)
    float  wA, wC;
    uint4  bn0, bn1, bn2, bn3;     // B frags (slice kk+1)

    auto loadB = [&](int kk) {
        const u16* p = bbase + kk * BK;
        bn0 = *(const uint4*)(p + 0 * 16 * KW);
        bn1 = *(const uint4*)(p + 1 * 16 * KW);
        bn2 = *(const uint4*)(p + 2 * 16 * KW);
        bn3 = *(const uint4*)(p + 3 * 16 * KW);
    };

    auto loadg = [&](int kk) {
        const int tap = kk >> 3;
        const int4 c = (tap == 0) ? cc0 : (tap == 1 ? cc1 : cc2);
        const int e0 = (kk & 7) * 32 + sub * 8;
        wA = __int_as_float(c.z);
        wC = __int_as_float(c.w);
        const float* rf = xb + (size_t)c.x * DIM + e0;
        const float* rc = xb + (size_t)c.y * DIM + e0;
        pf0 = *(const float4*)rf;
        pf1 = *(const float4*)(rf + 4);
        pc0 = *(const float4*)rc;
        pc1 = *(const float4*)(rc + 4);
    };

    auto packstore = [&](int buf) {
        float r0 = wA * pf0.x + wC * pc0.x;
        float r1 = wA * pf0.y + wC * pc0.y;
        float r2 = wA * pf0.z + wC * pc0.z;
        float r3 = wA * pf0.w + wC * pc0.w;
        float r4 = wA * pf1.x + wC * pc1.x;
        float r5 = wA * pf1.y + wC * pc1.y;
        float r6 = wA * pf1.z + wC * pc1.z;
        float r7 = wA * pf1.w + wC * pc1.w;
        uint32_t p0 = __builtin_amdgcn_perm(__float_as_uint(r1), __float_as_uint(r0), 0x07060302u);
        uint32_t p1 = __builtin_amdgcn_perm(__float_as_uint(r3), __float_as_uint(r2), 0x07060302u);
        uint32_t p2 = __builtin_amdgcn_perm(__float_as_uint(r5), __float_as_uint(r4), 0x07060302u);
        uint32_t p3 = __builtin_amdgcn_perm(__float_as_uint(r7), __float_as_uint(r6), 0x07060302u);
        *(uint4*)&As[buf][tl * 40 + sub * 8] = make_uint4(p0, p1, p2, p3);
    };

    // prologue: A slice 0 -> buf0; prefetch A slice 1, B slice 0
    loadg(0);
    packstore(0);
    loadg(1);
    loadB(0);

    floatx4 acc[4][4];
#pragma unroll
    for (int i = 0; i < 4; ++i)
#pragma unroll
        for (int j = 0; j < 4; ++j) acc[i][j] = (floatx4){0.f, 0.f, 0.f, 0.f};

    __syncthreads();                 // buf0 visible

    for (int kk = 0; kk < 24; ++kk) {
        const int cur = kk & 1;
        // consume B prefetch for slice kk
        bf16x8 bf0 = __builtin_bit_cast(bf16x8, bn0);
        bf16x8 bf1 = __builtin_bit_cast(bf16x8, bn1);
        bf16x8 bf2 = __builtin_bit_cast(bf16x8, bn2);
        bf16x8 bf3 = __builtin_bit_cast(bf16x8, bn3);
        // A fragments for slice kk from buf[cur] (whole 64-token tile)
        bf16x8 af[4];
#pragma unroll
        for (int i = 0; i < 4; ++i)
            af[i] = __builtin_bit_cast(bf16x8, *(const ushortx8*)&As[cur][(i * 16 + lrow) * 40 + lq * 8]);
        // issue next-slice B loads (L2-resident, static addresses)
        if (kk < 23) loadB(kk + 1);
        // stage A slice kk+1 into the OTHER buffer
        if (kk < 23) packstore(cur ^ 1);
        // refill A-gather prefetch with slice kk+2
        if (kk < 22) loadg(kk + 2);
#pragma unroll
        for (int i = 0; i < 4; ++i) {
            acc[i][0] = __builtin_amdgcn_mfma_f32_16x16x32_bf16(af[i], bf0, acc[i][0], 0, 0, 0);
            acc[i][1] = __builtin_amdgcn_mfma_f32_16x16x32_bf16(af[i], bf1, acc[i][1], 0, 0, 0);
            acc[i][2] = __builtin_amdgcn_mfma_f32_16x16x32_bf16(af[i], bf2, acc[i][2], 0, 0, 0);
            acc[i][3] = __builtin_amdgcn_mfma_f32_16x16x32_bf16(af[i], bf3, acc[i][3], 0, 0, 0);
        }
        __syncthreads();             // writes(kk)->reads(kk+1), reads(kk)->writes(kk+1)
    }

    // ---- epilogue: C/D layout col = lane&15, row = (lane>>4)*4 + reg
#pragma unroll
    for (int i = 0; i < 4; ++i) {
#pragma unroll
        for (int r = 0; r < 4; ++r) {
            const int token = t0 + i * 16 + lq * 4 + r;
            float* op = out + (size_t)token * DIM + wn + lrow;
#pragma unroll
            for (int j = 0; j < 4; ++j) op[j * 16] = acc[i][j][r];
        }
    }
}

extern "C" void kernel_launch(void* const* d_in, const int* in_sizes, int n_in,
                              void* d_out, int out_size, void* d_ws, size_t ws_size,
                              hipStream_t stream)
{
    const float* x    = (const float*)d_in[0];  // (8, 8192, 256)
    const float* offw = (const float*)d_in[1];  // (3, 256)
    const float* modw = (const float*)d_in[2];  // (3, 256)
    const float* W    = (const float*)d_in[3];  // (256, 256, 3)
    float* out = (float*)d_out;                 // (8, 8192, 256)

    const int tot_tok = 8 * N_TOK;              // 65536
    int4* coef = (int4*)d_ws;                                       // 3,145,728 B
    u16*  WB   = (u16*)((char*)d_ws + (size_t)tot_tok * 3 * 16);    //   393,216 B

    coef_kernel<<<tot_tok / 4, 256, 0, stream>>>(x, offw, modw, coef);
    packw_kernel<<<DIM, 256, 0, stream>>>(W, WB);
    deform_gemm_kernel<<<tot_tok / BM, 256, 0, stream>>>(x, WB, coef, out);
}

// Round 4
// 171.586 us; speedup vs baseline: 1.1997x; 1.1997x over previous
//
#include <hip/hip_runtime.h>
#include <hip/hip_bf16.h>
#include <cstdint>

// MxDNA deformable conv block, MI355X/gfx950.
// K2: W repack to FRAGMENT-LINEAR bf16 WB2[(kk*256+d)*32 + (kap&31)];
// K3: fused coef + gather-lerp + bf16 MFMA GEMM (M=65536, N=256, Kred=768).
// Round 5: XCD-aware bijective block swizzle (FETCH 203->69 MB).
// Round 6: BM64xBN256, 512thr, token gathered once (62.5 us).
// Round 7 (REGRESSED 90us): B direct from WB[d][kap] -- lane stride 1536 B
// made every B-load 16 scattered lines; TA-pipe bound + L2 thrash
// (FETCH 120 MB, WRITE 114 MB). Lesson: direct-global fragments need a
// fragment-linear layout.
// Round 8: (a) WB2 fragment-linear repack -> wave's B-frag load = one
// contiguous 1 KB, L2-resident, no LDS, no conflicts, no redundancy.
// A keeps R6's LDS dbuf (share gather across waves). LDS/blk-iter 68->20KB.
// (b) K1 fused into K3 prologue: block computes coef for its own 64 tokens
// (x rows t0..t0+63 read from L2, weights 6 KB staged in LDS) -- deletes a
// 64 MB HBM pass, 6 MB coef traffic, one launch.

#define N_TOK 8192
#define DIM   256
#define KW    768        // reduction length K*D
#define BM    64
#define BN    256
#define BK    32

typedef unsigned short u16;
typedef __attribute__((ext_vector_type(4))) float    floatx4;
typedef __attribute__((ext_vector_type(8))) __bf16   bf16x8;
typedef __attribute__((ext_vector_type(8))) u16      ushortx8;

__device__ __forceinline__ u16 f32_to_bf16_rne(float f) {
    uint32_t u = __float_as_uint(f);
    u += 0x7fffu + ((u >> 16) & 1u);
    return (u16)(u >> 16);
}

// ---------------- Kernel 2: repack weight, fragment-linear ----------------
// kap = k*256+e (reduction index); WB2[(kap>>5)*256 + d][kap&31].
// B-frag for (kk, col d): 32 contiguous bf16 (64 B) at ((kk*256+d)*32)*2.
__global__ __launch_bounds__(256) void packw_kernel(
    const float* __restrict__ W, u16* __restrict__ WB2)
{
    const int d = blockIdx.x;
    const int e = threadIdx.x;
#pragma unroll
    for (int k = 0; k < 3; ++k) {
        const int kap = k * 256 + e;
        WB2[((size_t)((kap >> 5) * 256 + d)) * 32 + (kap & 31)] =
            f32_to_bf16_rne(W[d * KW + e * 3 + k]);
    }
}

// ---------------- Kernel 3: fused coef + gather/lerp + MFMA GEMM ----------------
// block = 512 thr (8 waves), tile 64(M) x 256(N), BK=32, 24 K-iters.
// Wave tile 32x64 (2M x 4N grid of waves): acc 2x4 frags = 32 VGPR.
// A in LDS dbuf (rows padded to 40 shorts, 1 barrier/iter, gather prefetch
// dist 2); B fragments direct from fragment-linear WB2 (contiguous 1 KB per
// wave-load, L2-resident), register prefetch dist 1.
__global__ __launch_bounds__(512, 4) void deform_gemm_kernel(
    const float* __restrict__ x, const float* __restrict__ offw,
    const float* __restrict__ modw, const u16* __restrict__ WB2,
    float* __restrict__ out)
{
    __shared__ __align__(16) u16   As[2][BM * 40];   // 2 x 5120 B
    __shared__ __align__(16) float wlds[6 * DIM];    // offw rows 0-2, modw rows 3-5

    const int tid  = threadIdx.x;
    const int wave = tid >> 6;
    const int lane = tid & 63;

    // XCD-aware bijective swizzle: 1024 blocks, hw xcd = b % 8.
    // XCD x owns mtiles [x*128, (x+1)*128) == batch x.
    const int raw   = blockIdx.x;
    const int xcd   = raw & 7;
    const int lidx  = raw >> 3;              // 0..127 within XCD
    const int mtile = xcd * 128 + lidx;
    const int t0 = mtile * BM;
    const float* xb = x + (size_t)(t0 / N_TOK) * N_TOK * DIM;  // batch base (BM | N_TOK)

    // A roles: token tl (0..63), 4-float segment sub (0..7)
    const int tl  = tid >> 3;
    const int sub = tid & 7;

    const int wm = (wave & 1) * 32;   // wave M half
    const int wn = (wave >> 1) * 64;  // wave N quarter
    const int lrow = lane & 15;
    const int lq   = lane >> 4;

    // ---- fused coef computation for token t0+tl ----
    if (tid < 192)      ((float4*)wlds)[tid]       = ((const float4*)offw)[tid];
    else if (tid < 384) ((float4*)wlds)[tid]       = ((const float4*)modw)[tid - 192];
    __syncthreads();

    float s[6];
    {
        const float* xr = x + (size_t)(t0 + tl) * DIM + sub * 32;
        float4 xv[8];
#pragma unroll
        for (int i = 0; i < 8; ++i) xv[i] = ((const float4*)xr)[i];
#pragma unroll
        for (int w = 0; w < 6; ++w) {
            const float4* wr = (const float4*)(wlds + w * DIM + sub * 32);
            float a = 0.f;
#pragma unroll
            for (int i = 0; i < 8; ++i) {
                float4 wv = wr[i];
                a += xv[i].x * wv.x + xv[i].y * wv.y + xv[i].z * wv.z + xv[i].w * wv.w;
            }
            s[w] = a;
        }
    }
#pragma unroll
    for (int m = 1; m < 8; m <<= 1)
#pragma unroll
        for (int w = 0; w < 6; ++w) s[w] += __shfl_xor(s[w], m, 64);

    int fi0, fi1, fi2, ci0, ci1, ci2;
    float wa0, wa1, wa2, wc0, wc1, wc2;
    {
        const int n = (t0 + tl) & (N_TOK - 1);
#pragma unroll
        for (int k = 0; k < 3; ++k) {
            float pos   = (float)(n + k - 1) + s[k];
            bool  valid = (pos >= 0.0f) && (pos < (float)N_TOK);
            float ff = floorf(pos);
            ff = fminf(fmaxf(ff, 0.0f), (float)(N_TOK - 1));
            int   fi = (int)ff;
            int   ci = min(fi + 1, N_TOK - 1);
            float wc = pos - ff;
            float m  = valid ? (1.0f / (1.0f + expf(-s[3 + k]))) : 0.0f;
            float wa = (1.0f - wc) * m;
            float wcm = wc * m;
            if (k == 0) { fi0 = fi; ci0 = ci; wa0 = wa; wc0 = wcm; }
            if (k == 1) { fi1 = fi; ci1 = ci; wa1 = wa; wc1 = wcm; }
            if (k == 2) { fi2 = fi; ci2 = ci; wa2 = wa; wc2 = wcm; }
        }
    }

    // ---- pipeline registers ----
    float4 pf, pc;                 // A gather (slice kk+2)
    float  wA, wC;
    uint4  bn0, bn1, bn2, bn3;     // B frags (slice kk+1)

    auto loadB = [&](int kk) {
        const uint4* p = (const uint4*)(WB2 + ((size_t)(kk * 256 + wn + lrow)) * 32 + lq * 8);
        bn0 = p[0];      // col block j=0 (16 rows x 32 shorts = 64 uint4)
        bn1 = p[64];
        bn2 = p[128];
        bn3 = p[192];
    };

    auto loadg = [&](int kk) {
        const int tap = kk >> 3;
        const int fi = (tap == 0) ? fi0 : (tap == 1 ? fi1 : fi2);
        const int ci = (tap == 0) ? ci0 : (tap == 1 ? ci1 : ci2);
        wA = (tap == 0) ? wa0 : (tap == 1 ? wa1 : wa2);
        wC = (tap == 0) ? wc0 : (tap == 1 ? wc1 : wc2);
        const int e0 = (kk & 7) * 32 + sub * 4;
        pf = *(const float4*)(xb + (size_t)fi * DIM + e0);
        pc = *(const float4*)(xb + (size_t)ci * DIM + e0);
    };

    auto packstore = [&](int buf) {
        float r0 = wA * pf.x + wC * pc.x;
        float r1 = wA * pf.y + wC * pc.y;
        float r2 = wA * pf.z + wC * pc.z;
        float r3 = wA * pf.w + wC * pc.w;
        uint32_t p0 = __builtin_amdgcn_perm(__float_as_uint(r1), __float_as_uint(r0), 0x07060302u);
        uint32_t p1 = __builtin_amdgcn_perm(__float_as_uint(r3), __float_as_uint(r2), 0x07060302u);
        *(uint2*)&As[buf][tl * 40 + sub * 4] = make_uint2(p0, p1);
    };

    // prologue: A slice 0 -> buf0; prefetch A slice 1, B slice 0
    loadg(0);
    packstore(0);
    loadg(1);
    loadB(0);

    floatx4 acc[2][4];
#pragma unroll
    for (int i = 0; i < 2; ++i)
#pragma unroll
        for (int j = 0; j < 4; ++j) acc[i][j] = (floatx4){0.f, 0.f, 0.f, 0.f};

    __syncthreads();                 // buf0 visible

    for (int kk = 0; kk < 24; ++kk) {
        const int cur = kk & 1;
        // consume B prefetch for slice kk
        bf16x8 bf0 = __builtin_bit_cast(bf16x8, bn0);
        bf16x8 bf1 = __builtin_bit_cast(bf16x8, bn1);
        bf16x8 bf2 = __builtin_bit_cast(bf16x8, bn2);
        bf16x8 bf3 = __builtin_bit_cast(bf16x8, bn3);
        // A fragments for slice kk from buf[cur]
        bf16x8 af[2];
#pragma unroll
        for (int i = 0; i < 2; ++i)
            af[i] = __builtin_bit_cast(bf16x8, *(const ushortx8*)&As[cur][(wm + i * 16 + lrow) * 40 + lq * 8]);
        // issue next-slice B loads (contiguous 1 KB/wave, L2-resident)
        if (kk < 23) loadB(kk + 1);
        // stage A slice kk+1 into the OTHER buffer
        if (kk < 23) packstore(cur ^ 1);
        // refill A-gather prefetch with slice kk+2
        if (kk < 22) loadg(kk + 2);
#pragma unroll
        for (int i = 0; i < 2; ++i) {
            acc[i][0] = __builtin_amdgcn_mfma_f32_16x16x32_bf16(af[i], bf0, acc[i][0], 0, 0, 0);
            acc[i][1] = __builtin_amdgcn_mfma_f32_16x16x32_bf16(af[i], bf1, acc[i][1], 0, 0, 0);
            acc[i][2] = __builtin_amdgcn_mfma_f32_16x16x32_bf16(af[i], bf2, acc[i][2], 0, 0, 0);
            acc[i][3] = __builtin_amdgcn_mfma_f32_16x16x32_bf16(af[i], bf3, acc[i][3], 0, 0, 0);
        }
        __syncthreads();             // writes(kk)->reads(kk+1), reads(kk)->writes(kk+1)
    }

    // ---- epilogue: C/D layout col = lane&15, row = (lane>>4)*4 + reg
#pragma unroll
    for (int i = 0; i < 2; ++i) {
#pragma unroll
        for (int r = 0; r < 4; ++r) {
            const int token = t0 + wm + i * 16 + lq * 4 + r;
            float* op = out + (size_t)token * DIM + wn + lrow;
#pragma unroll
            for (int j = 0; j < 4; ++j) op[j * 16] = acc[i][j][r];
        }
    }
}

extern "C" void kernel_launch(void* const* d_in, const int* in_sizes, int n_in,
                              void* d_out, int out_size, void* d_ws, size_t ws_size,
                              hipStream_t stream)
{
    const float* x    = (const float*)d_in[0];  // (8, 8192, 256)
    const float* offw = (const float*)d_in[1];  // (3, 256)
    const float* modw = (const float*)d_in[2];  // (3, 256)
    const float* W    = (const float*)d_in[3];  // (256, 256, 3)
    float* out = (float*)d_out;                 // (8, 8192, 256)

    const int tot_tok = 8 * N_TOK;              // 65536
    u16* WB2 = (u16*)d_ws;                      // 393,216 B fragment-linear weight

    packw_kernel<<<DIM, 256, 0, stream>>>(W, WB2);
    deform_gemm_kernel<<<tot_tok / BM, 512, 0, stream>>>(x, offw, modw, WB2, out);
}

// Round 5
// 157.069 us; speedup vs baseline: 1.3106x; 1.0924x over previous
//
#include <hip/hip_runtime.h>
#include <hip/hip_bf16.h>
#include <cstdint>

// MxDNA deformable conv block, MI355X/gfx950.
// K2: W repack to FRAGMENT-LINEAR bf16 WB2[(kk*256+d)*32 + (kap&31)];
// K3: fused coef + gather-lerp + bf16 MFMA GEMM (M=65536, N=256, Kred=768).
// Round 5: XCD-aware bijective block swizzle (FETCH 203->69 MB).
// Round 6: BM64xBN256, 512thr, A+B LDS dbuf, token gathered once (62.5 us).
// Round 7/8 (REGRESSED): B direct-from-global in the MFMA loop loses ~24 us
// -- per-iter vmcnt in the MFMA critical path + per-wave (not per-block)
// B traffic. Lesson: B belongs in LDS; only its STAGING READ was bad in R6
// (lane stride 1536 B, 32 lines/wave-load).
// Round 9: R6 pipeline restored EXACTLY + R8's two keepers:
// (a) coef fused into prologue (-28 us: kills 64 MB x re-read + launch);
// (b) B staged from fragment-linear WB2 -> thread tid reads 32 contiguous
// bytes at WB2 + kk*16KB + tid*32 (coalesced), writes R6's proven Bs layout.

#define N_TOK 8192
#define DIM   256
#define KW    768        // reduction length K*D
#define BM    64
#define BN    256
#define BK    32

typedef unsigned short u16;
typedef __attribute__((ext_vector_type(4))) float    floatx4;
typedef __attribute__((ext_vector_type(8))) __bf16   bf16x8;
typedef __attribute__((ext_vector_type(8))) u16      ushortx8;

__device__ __forceinline__ u16 f32_to_bf16_rne(float f) {
    uint32_t u = __float_as_uint(f);
    u += 0x7fffu + ((u >> 16) & 1u);
    return (u16)(u >> 16);
}

// ---------------- Kernel 2: repack weight, fragment-linear ----------------
// kap = k*256+e (reduction index); slice kk = kap>>5 holds a contiguous
// 16 KB block of 256 rows (d) x 32 shorts (kap&31).
__global__ __launch_bounds__(256) void packw_kernel(
    const float* __restrict__ W, u16* __restrict__ WB2)
{
    const int d = blockIdx.x;
    const int e = threadIdx.x;
#pragma unroll
    for (int k = 0; k < 3; ++k) {
        const int kap = k * 256 + e;
        WB2[((size_t)((kap >> 5) * 256 + d)) * 32 + (kap & 31)] =
            f32_to_bf16_rne(W[d * KW + e * 3 + k]);
    }
}

// ---------------- Kernel 3: fused coef + gather/lerp + MFMA GEMM ----------------
// block = 512 thr (8 waves), tile 64(M) x 256(N), BK=32, 24 K-iters.
// Wave tile 32x64: acc 2x4 frags. A+B in LDS dbuf (rows padded to 40
// shorts), single end-of-iter barrier, register prefetch distance 2.
__global__ __launch_bounds__(512, 4) void deform_gemm_kernel(
    const float* __restrict__ x, const float* __restrict__ offw,
    const float* __restrict__ modw, const u16* __restrict__ WB2,
    float* __restrict__ out)
{
    __shared__ __align__(16) u16   As[2][BM * 40];   // 2 x  5120 B
    __shared__ __align__(16) u16   Bs[2][BN * 40];   // 2 x 20480 B
    __shared__ __align__(16) float wlds[6 * DIM];    // offw rows 0-2, modw rows 3-5

    const int tid  = threadIdx.x;
    const int wave = tid >> 6;
    const int lane = tid & 63;

    // XCD-aware bijective swizzle: 1024 blocks, hw xcd = b % 8.
    // XCD x owns mtiles [x*128, (x+1)*128) == batch x.
    const int raw   = blockIdx.x;
    const int xcd   = raw & 7;
    const int lidx  = raw >> 3;              // 0..127 within XCD
    const int mtile = xcd * 128 + lidx;
    const int t0 = mtile * BM;
    const float* xb = x + (size_t)(t0 / N_TOK) * N_TOK * DIM;  // batch base (BM | N_TOK)

    // A staging role: token tl (0..63), 4-float column segment sub (0..7)
    const int tl  = tid >> 3;
    const int sub = tid & 7;

    const int wm = (wave & 1) * 32;   // wave M half
    const int wn = (wave >> 1) * 64;  // wave N quarter
    const int lrow = lane & 15;
    const int lq   = lane >> 4;

    // ---- fused coef computation for token t0+tl (8 threads/token) ----
    if (tid < 192)      ((float4*)wlds)[tid] = ((const float4*)offw)[tid];
    else if (tid < 384) ((float4*)wlds)[tid] = ((const float4*)modw)[tid - 192];
    __syncthreads();

    float s[6];
    {
        const float* xr = x + (size_t)(t0 + tl) * DIM + sub * 32;
        float4 xv[8];
#pragma unroll
        for (int i = 0; i < 8; ++i) xv[i] = ((const float4*)xr)[i];
#pragma unroll
        for (int w = 0; w < 6; ++w) {
            const float4* wr = (const float4*)(wlds + w * DIM + sub * 32);
            float a = 0.f;
#pragma unroll
            for (int i = 0; i < 8; ++i) {
                float4 wv = wr[i];
                a += xv[i].x * wv.x + xv[i].y * wv.y + xv[i].z * wv.z + xv[i].w * wv.w;
            }
            s[w] = a;
        }
    }
#pragma unroll
    for (int m = 1; m < 8; m <<= 1)
#pragma unroll
        for (int w = 0; w < 6; ++w) s[w] += __shfl_xor(s[w], m, 64);

    int fi0, fi1, fi2, ci0, ci1, ci2;
    float wa0, wa1, wa2, wc0, wc1, wc2;
    {
        const int n = (t0 + tl) & (N_TOK - 1);
#pragma unroll
        for (int k = 0; k < 3; ++k) {
            float pos   = (float)(n + k - 1) + s[k];
            bool  valid = (pos >= 0.0f) && (pos < (float)N_TOK);
            float ff = floorf(pos);
            ff = fminf(fmaxf(ff, 0.0f), (float)(N_TOK - 1));
            int   fi = (int)ff;
            int   ci = min(fi + 1, N_TOK - 1);
            float wc = pos - ff;
            float m  = valid ? (1.0f / (1.0f + expf(-s[3 + k]))) : 0.0f;
            float wa = (1.0f - wc) * m;
            float wcm = wc * m;
            if (k == 0) { fi0 = fi; ci0 = ci; wa0 = wa; wc0 = wcm; }
            if (k == 1) { fi1 = fi; ci1 = ci; wa1 = wa; wc1 = wcm; }
            if (k == 2) { fi2 = fi; ci2 = ci; wa2 = wa; wc2 = wcm; }
        }
    }

    // ---- pipeline registers (prefetch distance 2) ----
    float4 pf, pc;       // A gather
    float  wA, wC;
    uint4  pb0, pb1;     // B staging (32 contiguous bytes per thread)

    auto loadg = [&](int kk) {
        const int tap = kk >> 3;
        const int fi = (tap == 0) ? fi0 : (tap == 1 ? fi1 : fi2);
        const int ci = (tap == 0) ? ci0 : (tap == 1 ? ci1 : ci2);
        wA = (tap == 0) ? wa0 : (tap == 1 ? wa1 : wa2);
        wC = (tap == 0) ? wc0 : (tap == 1 ? wc1 : wc2);
        const int e0 = (kk & 7) * 32 + sub * 4;
        pf = *(const float4*)(xb + (size_t)fi * DIM + e0);
        pc = *(const float4*)(xb + (size_t)ci * DIM + e0);
        // coalesced B staging read: slice kk is a contiguous 16 KB block
        const uint4* g = (const uint4*)(WB2 + (size_t)kk * 8192 + (size_t)tid * 16);
        pb0 = g[0];
        pb1 = g[1];
    };

    auto packstore = [&](int buf) {
        float r0 = wA * pf.x + wC * pc.x;
        float r1 = wA * pf.y + wC * pc.y;
        float r2 = wA * pf.z + wC * pc.z;
        float r3 = wA * pf.w + wC * pc.w;
        uint32_t p0 = __builtin_amdgcn_perm(__float_as_uint(r1), __float_as_uint(r0), 0x07060302u);
        uint32_t p1 = __builtin_amdgcn_perm(__float_as_uint(r3), __float_as_uint(r2), 0x07060302u);
        *(uint2*)&As[buf][tl * 40 + sub * 4] = make_uint2(p0, p1);
        // thread tid holds WB2 shorts [tid*16, tid*16+16) of the slice:
        // row d = tid>>1, kap half bh = tid&1 -> same Bs layout as R6
        uint4* bdst = (uint4*)&Bs[buf][(tid >> 1) * 40 + (tid & 1) * 16];
        bdst[0] = pb0;
        bdst[1] = pb1;
    };

    // prologue: slice 0 -> buf0; prefetch slice 1 into registers
    loadg(0);
    packstore(0);
    loadg(1);

    floatx4 acc[2][4];
#pragma unroll
    for (int i = 0; i < 2; ++i)
#pragma unroll
        for (int j = 0; j < 4; ++j) acc[i][j] = (floatx4){0.f, 0.f, 0.f, 0.f};

    __syncthreads();                 // buf0 visible

    for (int kk = 0; kk < 24; ++kk) {
        const int cur = kk & 1;
        // fragments for slice kk from buf[cur]
        bf16x8 af[2], bfv[4];
#pragma unroll
        for (int i = 0; i < 2; ++i)
            af[i] = __builtin_bit_cast(bf16x8, *(const ushortx8*)&As[cur][(wm + i * 16 + lrow) * 40 + lq * 8]);
#pragma unroll
        for (int j = 0; j < 4; ++j)
            bfv[j] = __builtin_bit_cast(bf16x8, *(const ushortx8*)&Bs[cur][(wn + j * 16 + lrow) * 40 + lq * 8]);
        // stage slice kk+1 into the OTHER buffer
        if (kk < 23) packstore(cur ^ 1);
        // refill prefetch registers with slice kk+2
        if (kk < 22) loadg(kk + 2);
#pragma unroll
        for (int i = 0; i < 2; ++i) {
            acc[i][0] = __builtin_amdgcn_mfma_f32_16x16x32_bf16(af[i], bfv[0], acc[i][0], 0, 0, 0);
            acc[i][1] = __builtin_amdgcn_mfma_f32_16x16x32_bf16(af[i], bfv[1], acc[i][1], 0, 0, 0);
            acc[i][2] = __builtin_amdgcn_mfma_f32_16x16x32_bf16(af[i], bfv[2], acc[i][2], 0, 0, 0);
            acc[i][3] = __builtin_amdgcn_mfma_f32_16x16x32_bf16(af[i], bfv[3], acc[i][3], 0, 0, 0);
        }
        __syncthreads();             // writes(kk)->reads(kk+1), reads(kk)->writes(kk+1)
    }

    // ---- epilogue: C/D layout col = lane&15, row = (lane>>4)*4 + reg
#pragma unroll
    for (int i = 0; i < 2; ++i) {
#pragma unroll
        for (int r = 0; r < 4; ++r) {
            const int token = t0 + wm + i * 16 + lq * 4 + r;
            float* op = out + (size_t)token * DIM + wn + lrow;
#pragma unroll
            for (int j = 0; j < 4; ++j) op[j * 16] = acc[i][j][r];
        }
    }
}

extern "C" void kernel_launch(void* const* d_in, const int* in_sizes, int n_in,
                              void* d_out, int out_size, void* d_ws, size_t ws_size,
                              hipStream_t stream)
{
    const float* x    = (const float*)d_in[0];  // (8, 8192, 256)
    const float* offw = (const float*)d_in[1];  // (3, 256)
    const float* modw = (const float*)d_in[2];  // (3, 256)
    const float* W    = (const float*)d_in[3];  // (256, 256, 3)
    float* out = (float*)d_out;                 // (8, 8192, 256)

    const int tot_tok = 8 * N_TOK;              // 65536
    u16* WB2 = (u16*)d_ws;                      // 393,216 B fragment-linear weight

    packw_kernel<<<DIM, 256, 0, stream>>>(W, WB2);
    deform_gemm_kernel<<<tot_tok / BM, 512, 0, stream>>>(x, offw, modw, WB2, out);
}